// Round 5
// baseline (104.457 us; speedup 1.0000x reference)
//
#include <hip/hip_runtime.h>
#include <hip/hip_bf16.h>
#include <hip/hip_fp8.h>

constexpr int B_ = 4, T_ = 256, N_ = 200, D_ = 64, H_ = 4;
constexpr int BN_ = B_ * N_;
constexpr float LN_EPS = 1e-5f;
// fold 1/sqrt(dh)=0.25 and log2(e) into Q so p = exp2(score)
constexpr float QSCALE = 0.25f * 1.4426950408889634f;

typedef short short8_t __attribute__((ext_vector_type(8)));
typedef float f32x4 __attribute__((ext_vector_type(4)));

#if __has_builtin(__builtin_amdgcn_exp2f)
#define EXP2(x) __builtin_amdgcn_exp2f(x)
#else
#define EXP2(x) exp2f(x)
#endif

// ---- arena (time-aliased) ----
// proj phase:  sWT bf16 [64][72] @ [0,9216)  (Wk, Wv, Wq staged serially)
// Qf8 [4h][256][16] @ [0,16384)      (written AFTER Wq frags consumed)
// Kf8 [4h][256][16] @ [16384,32768)
// Vf8 [64][272]     @ [32768,50176)
// epilogue: sAttn bf16 [256][72] @ [0,36864)   (over dead Q,K,V-head)
//           sWoT  bf16 [64][72]  @ [36864,46080) (over dead V)
constexpr int OFF_K  = 16384;
constexpr int OFF_V  = 32768;
constexpr int OFF_WO = 36864;
constexpr int ARENA_BYTES = 50176;   // 49 KiB -> 3 blocks/CU

__device__ __forceinline__ ushort f2bf(float f) {
    union { float f; unsigned u; } v; v.f = f;
    unsigned u = v.u + 0x7FFFu + ((v.u >> 16) & 1u);
    return (ushort)(u >> 16);
}

template <bool HI>
__device__ __forceinline__ unsigned cvt2fp8(float a, float b, unsigned old) {
#if __has_builtin(__builtin_amdgcn_cvt_pk_fp8_f32)
    return __builtin_amdgcn_cvt_pk_fp8_f32(a, b, old, HI);
#else
    __hip_fp8_e4m3 fa(a), fb(b);
    unsigned v = (unsigned)fa.__x | ((unsigned)fb.__x << 8);
    return HI ? ((old & 0x0000FFFFu) | (v << 16)) : ((old & 0xFFFF0000u) | v);
#endif
}

__device__ __forceinline__ f32x4 mfma_fp8(long long a, long long b, f32x4 c) {
    return __builtin_amdgcn_mfma_f32_16x16x32_fp8_fp8(a, b, c, 0, 0, 0);
}

__global__ __launch_bounds__(512, 6) void fused_attn_kernel(
    const float* __restrict__ X,
    const float* __restrict__ Wq, const float* __restrict__ bq,
    const float* __restrict__ Wk, const float* __restrict__ bk,
    const float* __restrict__ Wv, const float* __restrict__ bv,
    const float* __restrict__ Wo, const float* __restrict__ bo,
    const float* __restrict__ gamma, const float* __restrict__ beta,
    float* __restrict__ out)
{
    __shared__ __align__(16) unsigned char arena[ARENA_BYTES];
    unsigned char* Qf8 = arena;                 // [4][256][16] fp8
    unsigned char* Kf8 = arena + OFF_K;         // [4][256][16] fp8
    unsigned char* Vf8 = arena + OFF_V;         // [64][272]    fp8
    ushort* sWT   = (ushort*)arena;             // [64][72] bf16 transient
    ushort* sAttn = (ushort*)arena;             // [256][72] bf16 epilogue
    ushort* sWoT  = (ushort*)(arena + OFF_WO);  // [64][72] bf16 epilogue

    const int bn   = blockIdx.x;
    const int b    = bn / N_;
    const int n    = bn - b * N_;
    const int tid  = threadIdx.x;
    const int lane = tid & 63;
    const int w    = tid >> 6;        // wave 0..7
    const int lm   = lane & 15;
    const int g    = lane >> 4;       // 0..3
    const int wbase = w * 32;         // this wave's 32 X-rows for proj/epilogue

    const f32x4 zz = {0.f, 0.f, 0.f, 0.f};

    // ---------------- A/B-frags of X (rows wbase..wbase+31), bf16 in regs ----------
    short8_t af[2][2];
    #pragma unroll
    for (int mt = 0; mt < 2; ++mt) {
        #pragma unroll
        for (int kf = 0; kf < 2; ++kf) {
            const int t = wbase + mt * 16 + lm;
            const float* xp = X + (((long)(b * T_ + t)) * N_ + n) * D_ + kf * 32 + 8 * g;
            const float4 x0 = *(const float4*)xp;
            const float4 x1 = *(const float4*)(xp + 4);
            union { short8_t v; unsigned u[4]; } tmp;
            tmp.u[0] = ((unsigned)f2bf(x0.y) << 16) | f2bf(x0.x);
            tmp.u[1] = ((unsigned)f2bf(x0.w) << 16) | f2bf(x0.z);
            tmp.u[2] = ((unsigned)f2bf(x1.y) << 16) | f2bf(x1.x);
            tmp.u[3] = ((unsigned)f2bf(x1.w) << 16) | f2bf(x1.z);
            af[mt][kf] = tmp.v;
        }
    }

    // ---------------- QKV projections -> fp8 LDS (order: K, V, Q-last) -------------
    // K,Q computed swapped (lane holds 4 consecutive d at fixed q); V normal.
    const float* Wm[3] = {Wk, Wv, Wq};
    const float* bm[3] = {bk, bv, bq};
    #pragma unroll 1
    for (int m = 0; m < 3; ++m) {
        // stage W^T: pack two consecutive k per 4B write (halves conflict cycles)
        for (int idx = tid; idx < 2048; idx += 512) {
            const int c = idx & 63, kp = idx >> 6;   // kp in [0,32)
            const unsigned lo = f2bf(Wm[m][(2 * kp) * 64 + c]);
            const unsigned hi = f2bf(Wm[m][(2 * kp + 1) * 64 + c]);
            *(unsigned*)&sWT[c * 72 + 2 * kp] = lo | (hi << 16);
        }
        __syncthreads();

        short8_t bf[4][2];
        #pragma unroll
        for (int nt = 0; nt < 4; ++nt)
            #pragma unroll
            for (int kf = 0; kf < 2; ++kf)
                bf[nt][kf] = *(const short8_t*)&sWT[(nt * 16 + lm) * 72 + kf * 32 + 8 * g];

        __syncthreads();   // all frag reads done -> sWT region reusable (Qf8 / next W)

        if (m != 1) {
            // swapped: accT[dt][q2] rows d = dt*16+4g+r, col q = wbase+q2*16+lm
            f32x4 accT[4][2];
            #pragma unroll
            for (int dt = 0; dt < 4; ++dt)
                #pragma unroll
                for (int q2 = 0; q2 < 2; ++q2) {
                    accT[dt][q2] = zz;
                    #pragma unroll
                    for (int kf = 0; kf < 2; ++kf)
                        accT[dt][q2] = __builtin_amdgcn_mfma_f32_16x16x32_bf16(
                            bf[dt][kf], af[q2][kf], accT[dt][q2], 0, 0, 0);
                }

            unsigned char* dst = (m == 0) ? Kf8 : Qf8;
            const float scl = (m == 2) ? QSCALE : 1.0f;
            #pragma unroll
            for (int dt = 0; dt < 4; ++dt) {
                const float4 bI = *(const float4*)(bm[m] + dt * 16 + 4 * g);
                #pragma unroll
                for (int q2 = 0; q2 < 2; ++q2) {
                    const float v0 = (accT[dt][q2][0] + bI.x) * scl;
                    const float v1 = (accT[dt][q2][1] + bI.y) * scl;
                    const float v2 = (accT[dt][q2][2] + bI.z) * scl;
                    const float v3 = (accT[dt][q2][3] + bI.w) * scl;
                    unsigned pk = cvt2fp8<false>(v0, v1, 0u);
                    pk = cvt2fp8<true>(v2, v3, pk);
                    const int q = wbase + q2 * 16 + lm;
                    *(unsigned*)(dst + dt * 4096 + q * 16 + 4 * g) = pk;
                }
            }
        } else {
            // normal: accV[mt][nt] rows s = wbase+mt*16+4g+r, col d = nt*16+lm
            f32x4 accV[2][4];
            #pragma unroll
            for (int mt = 0; mt < 2; ++mt)
                #pragma unroll
                for (int nt = 0; nt < 4; ++nt) {
                    accV[mt][nt] = zz;
                    #pragma unroll
                    for (int kf = 0; kf < 2; ++kf)
                        accV[mt][nt] = __builtin_amdgcn_mfma_f32_16x16x32_bf16(
                            af[mt][kf], bf[nt][kf], accV[mt][nt], 0, 0, 0);
                }

            #pragma unroll
            for (int nt = 0; nt < 4; ++nt) {
                const float blv = bm[1][nt * 16 + lm];
                #pragma unroll
                for (int mt = 0; mt < 2; ++mt) {
                    const float v0 = accV[mt][nt][0] + blv;
                    const float v1 = accV[mt][nt][1] + blv;
                    const float v2 = accV[mt][nt][2] + blv;
                    const float v3 = accV[mt][nt][3] + blv;
                    unsigned pk = cvt2fp8<false>(v0, v1, 0u);
                    pk = cvt2fp8<true>(v2, v3, pk);
                    *(unsigned*)(Vf8 + (nt * 16 + lm) * 272 + wbase + mt * 16 + 4 * g) = pk;
                }
            }
        }
    }

    __syncthreads();   // Qf8/Kf8/Vf8 all visible

    // ---------------- attention: wave = (head h, query half) ------------------------
    const int h     = w >> 1;
    const int qbase = (w & 1) * 128;
    const bool glo  = (g < 2);   // dh=16 < K=32: lane groups 2,3 carry zeros in QK

    long long qf[8];
    #pragma unroll
    for (int qt = 0; qt < 8; ++qt)
        qf[qt] = glo ? *(const long long*)(Qf8 + h * 4096 + (qbase + qt * 16 + lm) * 16 + 8 * g)
                     : 0ll;

    f32x4 oacc[8];
    float lsum[8];
    #pragma unroll
    for (int qt = 0; qt < 8; ++qt) { oacc[qt] = zz; lsum[qt] = 0.f; }

    #pragma unroll 1
    for (int c = 0; c < 8; ++c) {
        const long long kfe = glo ? *(const long long*)(Kf8 + h * 4096 + ((2 * c) * 16 + lm) * 16 + 8 * g) : 0ll;
        const long long kfo = glo ? *(const long long*)(Kf8 + h * 4096 + ((2 * c + 1) * 16 + lm) * 16 + 8 * g) : 0ll;
        // V frag: byte j<4 -> s = 32c+4g+j ; j>=4 -> s = 32c+16+4g+(j-4); col d = h*16+lm
        const unsigned va = *(const unsigned*)(Vf8 + (h * 16 + lm) * 272 + 32 * c + 4 * g);
        const unsigned vb = *(const unsigned*)(Vf8 + (h * 16 + lm) * 272 + 32 * c + 16 + 4 * g);
        const long long vf = (long long)(((unsigned long long)vb << 32) | va);

        #pragma unroll
        for (int qt = 0; qt < 8; ++qt) {
            const f32x4 se = mfma_fp8(kfe, qf[qt], zz);   // rows s=32c+4g+r, col q=lm
            const f32x4 so = mfma_fp8(kfo, qf[qt], zz);   // rows s=32c+16+4g+r
            const float pe0 = EXP2(se[0]), pe1 = EXP2(se[1]);
            const float pe2 = EXP2(se[2]), pe3 = EXP2(se[3]);
            const float po0 = EXP2(so[0]), po1 = EXP2(so[1]);
            const float po2 = EXP2(so[2]), po3 = EXP2(so[3]);
            lsum[qt] += ((pe0 + pe1) + (pe2 + pe3)) + ((po0 + po1) + (po2 + po3));
            unsigned a0 = cvt2fp8<false>(pe0, pe1, 0u); a0 = cvt2fp8<true>(pe2, pe3, a0);
            unsigned a1 = cvt2fp8<false>(po0, po1, 0u); a1 = cvt2fp8<true>(po2, po3, a1);
            const long long pa = (long long)(((unsigned long long)a1 << 32) | a0);
            oacc[qt] = mfma_fp8(pa, vf, oacc[qt]);
        }
    }

    float inv[8];
    #pragma unroll
    for (int qt = 0; qt < 8; ++qt) {
        float t0 = lsum[qt] + __shfl_xor(lsum[qt], 16, 64);
        t0 += __shfl_xor(t0, 32, 64);
        inv[qt] = 1.0f / t0;
    }

    __syncthreads();   // all waves done reading Qf8/Kf8/Vf8 -> alias as sAttn/sWoT

    // write normalized attention out (bf16) + stage Wo^T into dead V space
    #pragma unroll
    for (int qt = 0; qt < 8; ++qt)
        #pragma unroll
        for (int r = 0; r < 4; ++r) {
            const float iv = __shfl(inv[qt], 4 * g + r, 64);
            sAttn[(qbase + qt * 16 + 4 * g + r) * 72 + h * 16 + lm] = f2bf(oacc[qt][r] * iv);
        }
    for (int idx = tid; idx < 2048; idx += 512) {
        const int c = idx & 63, kp = idx >> 6;
        const unsigned lo = f2bf(Wo[(2 * kp) * 64 + c]);
        const unsigned hi = f2bf(Wo[(2 * kp + 1) * 64 + c]);
        *(unsigned*)&sWoT[c * 72 + 2 * kp] = lo | (hi << 16);
    }

    __syncthreads();

    // ---------------- Wo projection + bias + residual + LayerNorm -------------------
    short8_t wf[4][2];
    #pragma unroll
    for (int nt = 0; nt < 4; ++nt)
        #pragma unroll
        for (int kf = 0; kf < 2; ++kf)
            wf[nt][kf] = *(const short8_t*)&sWoT[(nt * 16 + lm) * 72 + kf * 32 + 8 * g];

    short8_t aF[2][2];
    #pragma unroll
    for (int mt = 0; mt < 2; ++mt)
        #pragma unroll
        for (int kf = 0; kf < 2; ++kf)
            aF[mt][kf] = *(const short8_t*)&sAttn[(wbase + mt * 16 + lm) * 72 + kf * 32 + 8 * g];

    f32x4 acc2[2][4];
    #pragma unroll
    for (int mt = 0; mt < 2; ++mt)
        #pragma unroll
        for (int nt = 0; nt < 4; ++nt) {
            acc2[mt][nt] = zz;
            #pragma unroll
            for (int kf = 0; kf < 2; ++kf)
                acc2[mt][nt] = __builtin_amdgcn_mfma_f32_16x16x32_bf16(
                    aF[mt][kf], wf[nt][kf], acc2[mt][nt], 0, 0, 0);
        }

    float bo_l[4], ga_l[4], be_l[4];
    #pragma unroll
    for (int nt = 0; nt < 4; ++nt) {
        bo_l[nt] = bo[nt * 16 + lm];
        ga_l[nt] = gamma[nt * 16 + lm];
        be_l[nt] = beta[nt * 16 + lm];
    }

    #pragma unroll
    for (int mt = 0; mt < 2; ++mt)
        #pragma unroll
        for (int r = 0; r < 4; ++r) {
            const int t = wbase + mt * 16 + 4 * g + r;
            const long base = (((long)(b * T_ + t)) * N_ + n) * D_;
            float v[4];
            #pragma unroll
            for (int nt = 0; nt < 4; ++nt)
                v[nt] = acc2[mt][nt][r] + bo_l[nt] + X[base + nt * 16 + lm];
            float s1 = (v[0] + v[1]) + (v[2] + v[3]);
            float s2 = (v[0] * v[0] + v[1] * v[1]) + (v[2] * v[2] + v[3] * v[3]);
            #pragma unroll
            for (int m = 1; m <= 8; m <<= 1) {
                s1 += __shfl_xor(s1, m, 64);
                s2 += __shfl_xor(s2, m, 64);
            }
            const float mu  = s1 * 0.015625f;
            const float var = s2 * 0.015625f - mu * mu;
            const float rs  = rsqrtf(var + LN_EPS);
            #pragma unroll
            for (int nt = 0; nt < 4; ++nt)
                out[base + nt * 16 + lm] = (v[nt] - mu) * rs * ga_l[nt] + be_l[nt];
        }
}

extern "C" void kernel_launch(void* const* d_in, const int* in_sizes, int n_in,
                              void* d_out, int out_size, void* d_ws, size_t ws_size,
                              hipStream_t stream) {
    const float* X     = (const float*)d_in[0];
    const float* Wq    = (const float*)d_in[1];
    const float* bq    = (const float*)d_in[2];
    const float* Wk    = (const float*)d_in[3];
    const float* bk    = (const float*)d_in[4];
    const float* Wv    = (const float*)d_in[5];
    const float* bv    = (const float*)d_in[6];
    const float* Wo    = (const float*)d_in[7];
    const float* bo    = (const float*)d_in[8];
    const float* gamma = (const float*)d_in[9];
    const float* beta  = (const float*)d_in[10];

    fused_attn_kernel<<<BN_, 512, 0, stream>>>(
        X, Wq, bq, Wk, bk, Wv, bv, Wo, bo, gamma, beta, (float*)d_out);
}

// Round 6
// 74.600 us; speedup vs baseline: 1.4002x; 1.4002x over previous
//
#include <hip/hip_runtime.h>
#include <hip/hip_bf16.h>
#include <hip/hip_fp8.h>

constexpr int B_ = 4, T_ = 256, N_ = 200, D_ = 64, H_ = 4;
constexpr int BN_ = B_ * N_;
constexpr float LN_EPS = 1e-5f;
// fold 1/sqrt(dh)=0.25 and log2(e) into Q so p = exp2(score)
constexpr float QSCALE = 0.25f * 1.4426950408889634f;

typedef short short8_t __attribute__((ext_vector_type(8)));
typedef float f32x4 __attribute__((ext_vector_type(4)));

#if __has_builtin(__builtin_amdgcn_exp2f)
#define EXP2(x) __builtin_amdgcn_exp2f(x)
#else
#define EXP2(x) exp2f(x)
#endif

// ---- arena (time-aliased) ----
// proj phase:  sWT bf16 [64][72] @ [0,9216)  (Wk, Wv, Wq staged serially)
// Qf8 [4h][256][16] @ [0,16384)      (written AFTER Wq frags consumed)
// Kf8 [4h][256][16] @ [16384,32768)
// Vf8 [64][272]     @ [32768,50176)
// epilogue: sAttn bf16 [256][72] @ [0,36864)   (over dead Q,K,V-head)
//           sWoT  bf16 [64][72]  @ [36864,46080) (over dead V)
constexpr int OFF_K  = 16384;
constexpr int OFF_V  = 32768;
constexpr int OFF_WO = 36864;
constexpr int ARENA_BYTES = 50176;   // 49 KiB -> LDS allows 3 blocks/CU

__device__ __forceinline__ ushort f2bf(float f) {
    union { float f; unsigned u; } v; v.f = f;
    unsigned u = v.u + 0x7FFFu + ((v.u >> 16) & 1u);
    return (ushort)(u >> 16);
}

template <bool HI>
__device__ __forceinline__ unsigned cvt2fp8(float a, float b, unsigned old) {
#if __has_builtin(__builtin_amdgcn_cvt_pk_fp8_f32)
    return __builtin_amdgcn_cvt_pk_fp8_f32(a, b, old, HI);
#else
    __hip_fp8_e4m3 fa(a), fb(b);
    unsigned v = (unsigned)fa.__x | ((unsigned)fb.__x << 8);
    return HI ? ((old & 0x0000FFFFu) | (v << 16)) : ((old & 0xFFFF0000u) | v);
#endif
}

__device__ __forceinline__ f32x4 mfma_fp8(long long a, long long b, f32x4 c) {
    return __builtin_amdgcn_mfma_f32_16x16x32_fp8_fp8(a, b, c, 0, 0, 0);
}

// (512,4): allocator floor 4 waves/SIMD -> no spills (r4: 60 VGPR <= 64).
// Runtime occupancy is then LDS-bound at 3 blocks/CU (24 waves) since 60<=64
// allows 8 waves/SIMD register-wise. (512,6) forced spills: 40 VGPR + 140MB
// scratch traffic, dur 104us (round 5 post-mortem).
__global__ __launch_bounds__(512, 4) void fused_attn_kernel(
    const float* __restrict__ X,
    const float* __restrict__ Wq, const float* __restrict__ bq,
    const float* __restrict__ Wk, const float* __restrict__ bk,
    const float* __restrict__ Wv, const float* __restrict__ bv,
    const float* __restrict__ Wo, const float* __restrict__ bo,
    const float* __restrict__ gamma, const float* __restrict__ beta,
    float* __restrict__ out)
{
    __shared__ __align__(16) unsigned char arena[ARENA_BYTES];
    unsigned char* Qf8 = arena;                 // [4][256][16] fp8
    unsigned char* Kf8 = arena + OFF_K;         // [4][256][16] fp8
    unsigned char* Vf8 = arena + OFF_V;         // [64][272]    fp8
    ushort* sWT   = (ushort*)arena;             // [64][72] bf16 transient
    ushort* sAttn = (ushort*)arena;             // [256][72] bf16 epilogue
    ushort* sWoT  = (ushort*)(arena + OFF_WO);  // [64][72] bf16 epilogue

    const int bn   = blockIdx.x;
    const int b    = bn / N_;
    const int n    = bn - b * N_;
    const int tid  = threadIdx.x;
    const int lane = tid & 63;
    const int w    = tid >> 6;        // wave 0..7
    const int lm   = lane & 15;
    const int g    = lane >> 4;       // 0..3
    const int wbase = w * 32;         // this wave's 32 X-rows for proj/epilogue

    const f32x4 zz = {0.f, 0.f, 0.f, 0.f};

    // ---------------- A/B-frags of X (rows wbase..wbase+31), bf16 in regs ----------
    short8_t af[2][2];
    #pragma unroll
    for (int mt = 0; mt < 2; ++mt) {
        #pragma unroll
        for (int kf = 0; kf < 2; ++kf) {
            const int t = wbase + mt * 16 + lm;
            const float* xp = X + (((long)(b * T_ + t)) * N_ + n) * D_ + kf * 32 + 8 * g;
            const float4 x0 = *(const float4*)xp;
            const float4 x1 = *(const float4*)(xp + 4);
            union { short8_t v; unsigned u[4]; } tmp;
            tmp.u[0] = ((unsigned)f2bf(x0.y) << 16) | f2bf(x0.x);
            tmp.u[1] = ((unsigned)f2bf(x0.w) << 16) | f2bf(x0.z);
            tmp.u[2] = ((unsigned)f2bf(x1.y) << 16) | f2bf(x1.x);
            tmp.u[3] = ((unsigned)f2bf(x1.w) << 16) | f2bf(x1.z);
            af[mt][kf] = tmp.v;
        }
    }

    // ---------------- QKV projections -> fp8 LDS (order: K, V, Q-last) -------------
    // K,Q computed swapped (lane holds 4 consecutive d at fixed q); V normal.
    const float* Wm[3] = {Wk, Wv, Wq};
    const float* bm[3] = {bk, bv, bq};
    #pragma unroll 1
    for (int m = 0; m < 3; ++m) {
        // stage W^T: pack two consecutive k per 4B write (halves conflict cycles)
        for (int idx = tid; idx < 2048; idx += 512) {
            const int c = idx & 63, kp = idx >> 6;   // kp in [0,32)
            const unsigned lo = f2bf(Wm[m][(2 * kp) * 64 + c]);
            const unsigned hi = f2bf(Wm[m][(2 * kp + 1) * 64 + c]);
            *(unsigned*)&sWT[c * 72 + 2 * kp] = lo | (hi << 16);
        }
        __syncthreads();

        short8_t bf[4][2];
        #pragma unroll
        for (int nt = 0; nt < 4; ++nt)
            #pragma unroll
            for (int kf = 0; kf < 2; ++kf)
                bf[nt][kf] = *(const short8_t*)&sWT[(nt * 16 + lm) * 72 + kf * 32 + 8 * g];

        __syncthreads();   // all frag reads done -> sWT region reusable (Qf8 / next W)

        if (m != 1) {
            // swapped: accT[dt][q2] rows d = dt*16+4g+r, col q = wbase+q2*16+lm
            f32x4 accT[4][2];
            #pragma unroll
            for (int dt = 0; dt < 4; ++dt)
                #pragma unroll
                for (int q2 = 0; q2 < 2; ++q2) {
                    accT[dt][q2] = zz;
                    #pragma unroll
                    for (int kf = 0; kf < 2; ++kf)
                        accT[dt][q2] = __builtin_amdgcn_mfma_f32_16x16x32_bf16(
                            bf[dt][kf], af[q2][kf], accT[dt][q2], 0, 0, 0);
                }

            unsigned char* dst = (m == 0) ? Kf8 : Qf8;
            const float scl = (m == 2) ? QSCALE : 1.0f;
            #pragma unroll
            for (int dt = 0; dt < 4; ++dt) {
                const float4 bI = *(const float4*)(bm[m] + dt * 16 + 4 * g);
                #pragma unroll
                for (int q2 = 0; q2 < 2; ++q2) {
                    const float v0 = (accT[dt][q2][0] + bI.x) * scl;
                    const float v1 = (accT[dt][q2][1] + bI.y) * scl;
                    const float v2 = (accT[dt][q2][2] + bI.z) * scl;
                    const float v3 = (accT[dt][q2][3] + bI.w) * scl;
                    unsigned pk = cvt2fp8<false>(v0, v1, 0u);
                    pk = cvt2fp8<true>(v2, v3, pk);
                    const int q = wbase + q2 * 16 + lm;
                    *(unsigned*)(dst + dt * 4096 + q * 16 + 4 * g) = pk;
                }
            }
        } else {
            // normal: accV[mt][nt] rows s = wbase+mt*16+4g+r, col d = nt*16+lm
            f32x4 accV[2][4];
            #pragma unroll
            for (int mt = 0; mt < 2; ++mt)
                #pragma unroll
                for (int nt = 0; nt < 4; ++nt) {
                    accV[mt][nt] = zz;
                    #pragma unroll
                    for (int kf = 0; kf < 2; ++kf)
                        accV[mt][nt] = __builtin_amdgcn_mfma_f32_16x16x32_bf16(
                            af[mt][kf], bf[nt][kf], accV[mt][nt], 0, 0, 0);
                }

            #pragma unroll
            for (int nt = 0; nt < 4; ++nt) {
                const float blv = bm[1][nt * 16 + lm];
                #pragma unroll
                for (int mt = 0; mt < 2; ++mt) {
                    const float v0 = accV[mt][nt][0] + blv;
                    const float v1 = accV[mt][nt][1] + blv;
                    const float v2 = accV[mt][nt][2] + blv;
                    const float v3 = accV[mt][nt][3] + blv;
                    unsigned pk = cvt2fp8<false>(v0, v1, 0u);
                    pk = cvt2fp8<true>(v2, v3, pk);
                    *(unsigned*)(Vf8 + (nt * 16 + lm) * 272 + wbase + mt * 16 + 4 * g) = pk;
                }
            }
        }
    }

    __syncthreads();   // Qf8/Kf8/Vf8 all visible

    // ---------------- attention: wave = (head h, query half) ------------------------
    const int h     = w >> 1;
    const int qbase = (w & 1) * 128;
    const bool glo  = (g < 2);   // dh=16 < K=32: lane groups 2,3 carry zeros in QK

    long long qf[8];
    #pragma unroll
    for (int qt = 0; qt < 8; ++qt)
        qf[qt] = glo ? *(const long long*)(Qf8 + h * 4096 + (qbase + qt * 16 + lm) * 16 + 8 * g)
                     : 0ll;

    f32x4 oacc[8];
    float lsum[8];
    #pragma unroll
    for (int qt = 0; qt < 8; ++qt) { oacc[qt] = zz; lsum[qt] = 0.f; }

    #pragma unroll 1
    for (int c = 0; c < 8; ++c) {
        const long long kfe = glo ? *(const long long*)(Kf8 + h * 4096 + ((2 * c) * 16 + lm) * 16 + 8 * g) : 0ll;
        const long long kfo = glo ? *(const long long*)(Kf8 + h * 4096 + ((2 * c + 1) * 16 + lm) * 16 + 8 * g) : 0ll;
        // V frag: byte j<4 -> s = 32c+4g+j ; j>=4 -> s = 32c+16+4g+(j-4); col d = h*16+lm
        const unsigned va = *(const unsigned*)(Vf8 + (h * 16 + lm) * 272 + 32 * c + 4 * g);
        const unsigned vb = *(const unsigned*)(Vf8 + (h * 16 + lm) * 272 + 32 * c + 16 + 4 * g);
        const long long vf = (long long)(((unsigned long long)vb << 32) | va);

        #pragma unroll
        for (int qt = 0; qt < 8; ++qt) {
            const f32x4 se = mfma_fp8(kfe, qf[qt], zz);   // rows s=32c+4g+r, col q=lm
            const f32x4 so = mfma_fp8(kfo, qf[qt], zz);   // rows s=32c+16+4g+r
            const float pe0 = EXP2(se[0]), pe1 = EXP2(se[1]);
            const float pe2 = EXP2(se[2]), pe3 = EXP2(se[3]);
            const float po0 = EXP2(so[0]), po1 = EXP2(so[1]);
            const float po2 = EXP2(so[2]), po3 = EXP2(so[3]);
            lsum[qt] += ((pe0 + pe1) + (pe2 + pe3)) + ((po0 + po1) + (po2 + po3));
            unsigned a0 = cvt2fp8<false>(pe0, pe1, 0u); a0 = cvt2fp8<true>(pe2, pe3, a0);
            unsigned a1 = cvt2fp8<false>(po0, po1, 0u); a1 = cvt2fp8<true>(po2, po3, a1);
            const long long pa = (long long)(((unsigned long long)a1 << 32) | a0);
            oacc[qt] = mfma_fp8(pa, vf, oacc[qt]);
        }
    }

    float inv[8];
    #pragma unroll
    for (int qt = 0; qt < 8; ++qt) {
        float t0 = lsum[qt] + __shfl_xor(lsum[qt], 16, 64);
        t0 += __shfl_xor(t0, 32, 64);
        inv[qt] = 1.0f / t0;
    }

    __syncthreads();   // all waves done reading Qf8/Kf8/Vf8 -> alias as sAttn/sWoT

    // write normalized attention out (bf16) + stage Wo^T into dead V space
    #pragma unroll
    for (int qt = 0; qt < 8; ++qt)
        #pragma unroll
        for (int r = 0; r < 4; ++r) {
            const float iv = __shfl(inv[qt], 4 * g + r, 64);
            sAttn[(qbase + qt * 16 + 4 * g + r) * 72 + h * 16 + lm] = f2bf(oacc[qt][r] * iv);
        }
    for (int idx = tid; idx < 2048; idx += 512) {
        const int c = idx & 63, kp = idx >> 6;
        const unsigned lo = f2bf(Wo[(2 * kp) * 64 + c]);
        const unsigned hi = f2bf(Wo[(2 * kp + 1) * 64 + c]);
        *(unsigned*)&sWoT[c * 72 + 2 * kp] = lo | (hi << 16);
    }

    __syncthreads();

    // ---------------- Wo projection + bias + residual + LayerNorm -------------------
    short8_t wf[4][2];
    #pragma unroll
    for (int nt = 0; nt < 4; ++nt)
        #pragma unroll
        for (int kf = 0; kf < 2; ++kf)
            wf[nt][kf] = *(const short8_t*)&sWoT[(nt * 16 + lm) * 72 + kf * 32 + 8 * g];

    short8_t aF[2][2];
    #pragma unroll
    for (int mt = 0; mt < 2; ++mt)
        #pragma unroll
        for (int kf = 0; kf < 2; ++kf)
            aF[mt][kf] = *(const short8_t*)&sAttn[(wbase + mt * 16 + lm) * 72 + kf * 32 + 8 * g];

    f32x4 acc2[2][4];
    #pragma unroll
    for (int mt = 0; mt < 2; ++mt)
        #pragma unroll
        for (int nt = 0; nt < 4; ++nt) {
            acc2[mt][nt] = zz;
            #pragma unroll
            for (int kf = 0; kf < 2; ++kf)
                acc2[mt][nt] = __builtin_amdgcn_mfma_f32_16x16x32_bf16(
                    aF[mt][kf], wf[nt][kf], acc2[mt][nt], 0, 0, 0);
        }

    float bo_l[4], ga_l[4], be_l[4];
    #pragma unroll
    for (int nt = 0; nt < 4; ++nt) {
        bo_l[nt] = bo[nt * 16 + lm];
        ga_l[nt] = gamma[nt * 16 + lm];
        be_l[nt] = beta[nt * 16 + lm];
    }

    #pragma unroll
    for (int mt = 0; mt < 2; ++mt)
        #pragma unroll
        for (int r = 0; r < 4; ++r) {
            const int t = wbase + mt * 16 + 4 * g + r;
            const long base = (((long)(b * T_ + t)) * N_ + n) * D_;
            float v[4];
            #pragma unroll
            for (int nt = 0; nt < 4; ++nt)
                v[nt] = acc2[mt][nt][r] + bo_l[nt] + X[base + nt * 16 + lm];
            float s1 = (v[0] + v[1]) + (v[2] + v[3]);
            float s2 = (v[0] * v[0] + v[1] * v[1]) + (v[2] * v[2] + v[3] * v[3]);
            #pragma unroll
            for (int m = 1; m <= 8; m <<= 1) {
                s1 += __shfl_xor(s1, m, 64);
                s2 += __shfl_xor(s2, m, 64);
            }
            const float mu  = s1 * 0.015625f;
            const float var = s2 * 0.015625f - mu * mu;
            const float rs  = rsqrtf(var + LN_EPS);
            #pragma unroll
            for (int nt = 0; nt < 4; ++nt)
                out[base + nt * 16 + lm] = (v[nt] - mu) * rs * ga_l[nt] + be_l[nt];
        }
}

extern "C" void kernel_launch(void* const* d_in, const int* in_sizes, int n_in,
                              void* d_out, int out_size, void* d_ws, size_t ws_size,
                              hipStream_t stream) {
    const float* X     = (const float*)d_in[0];
    const float* Wq    = (const float*)d_in[1];
    const float* bq    = (const float*)d_in[2];
    const float* Wk    = (const float*)d_in[3];
    const float* bk    = (const float*)d_in[4];
    const float* Wv    = (const float*)d_in[5];
    const float* bv    = (const float*)d_in[6];
    const float* Wo    = (const float*)d_in[7];
    const float* bo    = (const float*)d_in[8];
    const float* gamma = (const float*)d_in[9];
    const float* beta  = (const float*)d_in[10];

    fused_attn_kernel<<<BN_, 512, 0, stream>>>(
        X, Wq, bq, Wk, bk, Wv, bv, Wo, bo, gamma, beta, (float*)d_out);
}